// Round 5
// baseline (57.563 us; speedup 1.0000x reference)
//
#include <hip/hip_runtime.h>
#include <hip/hip_bf16.h>

#define MM    512
#define NROWS 36          // rolling LDS row buffer: slot(imgrow R) = (R+1) % 36
#define ROWSZ (66 * 8)    // shorts per LDS row (66 cols x 8 ch)

typedef short bf16x8 __attribute__((ext_vector_type(8)));
typedef float f32x4  __attribute__((ext_vector_type(4)));

static __device__ inline short f2bf(float f) {
    __hip_bfloat16 h = __float2bfloat16(f);
    return *reinterpret_cast<short*>(&h);
}

// One block per output row b in [0,2048): e = b>>9, sample = idx[b].
// GEMM per 16-pixel tile: D[16px,16co] = A[16,96] @ B[96,16]
//   B cols 0-7  = W1 (center tap, k=32..39) ; B cols 8-15 = W3 (taps 0..8)
// sx (skip channel sums) via identity-B MFMA on the center-tap A frag.
// pooled = mean relu + (mean x)@Wskip ; out = (pooled@Wd)*mask
//
// Rolling mod-36 row buffer: every image row is fetched from HBM exactly
// once (no strip-halo re-read). Prefetch slots for strip s+1 are disjoint
// from strip-s read slots -> single barrier per strip, async T14 staging.
// a2 (tap 8) LDS read exec-masked to lane-group 0 (B rows k>=72 are zero).
__global__ __launch_bounds__(256, 4)
void conv_moe_mfma(const float* __restrict__ x,
                   const int*   __restrict__ idx,
                   const float* __restrict__ W1,
                   const float* __restrict__ W3,
                   const float* __restrict__ Wsk,
                   const float* __restrict__ Wd,
                   const float* __restrict__ cmask,
                   float*       __restrict__ out)
{
    __shared__ short xbf[NROWS][66][8];   // 38,016 B, col halo at 0 and 65
    __shared__ float red[4][16];
    __shared__ float redx[4][8];
    __shared__ float rsum[16];
    __shared__ float rsumx[8];
    __shared__ float pooledS[16];

    const int b    = blockIdx.x;
    const int e    = b >> 9;
    const int tid  = threadIdx.x;
    const int lane = tid & 63;
    const int wid  = tid >> 6;
    const int g    = lane >> 4;   // lane group 0..3
    const int p    = lane & 15;   // A: pixel row; B/D: cout column
    const int CB   = wid << 4;    // this wave's 16-col tile base

    const int samp = idx[b];
    const float* xb = x + (size_t)samp * 32768;

    // ---- B fragments (constant per block) ----
    const float* w3 = W3 + e * 576;  // [tap][cin][cout] (tap=kh*3+kw)
    const float* w1 = W1 + e * 64;   // [cin][cout]
    bf16x8 bf0, bf1, bf2, bid;
    #pragma unroll
    for (int j = 0; j < 8; ++j) {
        float v0 = 0.f, v1 = 0.f, v2 = 0.f, vi = 0.f;
        if (p >= 8) {                       // conv3 couts
            v0 = w3[g * 64 + j * 8 + (p - 8)];             // taps 0..3
            v1 = w3[(4 + g) * 64 + j * 8 + (p - 8)];       // taps 4..7
            if (g == 0) v2 = w3[8 * 64 + j * 8 + (p - 8)]; // tap 8
        } else {                            // conv1 couts (center tap = k 32..39)
            if (g == 0) { v1 = w1[j * 8 + p]; vi = (j == p) ? 1.f : 0.f; }
        }
        bf0[j] = f2bf(v0); bf1[j] = f2bf(v1); bf2[j] = f2bf(v2); bid[j] = f2bf(vi);
    }

    // ---- per-lane A-read constants ----
    const int d0 = g / 3;                    // tap g:    dr
    const int d1 = (4 + g) / 3;              // tap 4+g:  dr
    const int c0 = (CB + p + (g % 3)) * 8;       // col offset (shorts)
    const int c1 = (CB + p + ((4 + g) % 3)) * 8;
    const int c2 = (CB + p + 2) * 8;             // tap 8 (dr=2,dc=2)

    // ---- zero column halos once (cols 0 and 65, all 36 rows) ----
    if (tid < 72) {
        const int rr = tid >> 1, side = tid & 1;
        bf16x8 zv = {0,0,0,0,0,0,0,0};
        *(bf16x8*)&xbf[rr][side ? 65 : 0][0] = zv;
    }

    const float4 z4 = make_float4(0.f, 0.f, 0.f, 0.f);
    float4 ra[5][2];   // in-flight rows: up to 4.5 px x 32B per thread

    // ---- initial stage: image rows -1..16 -> slots 0..17 (1152 px) ----
    #pragma unroll
    for (int j5 = 0; j5 < 5; ++j5) {
        const int j = j5 * 256 + tid;
        ra[j5][0] = z4; ra[j5][1] = z4;
        if (j < 1152) {
            const int lrow = j >> 6, c = j & 63;
            const int r = lrow - 1;          // -1..16, upper bound always ok
            if (r >= 0) {
                const float4* s4 = (const float4*)(xb + (((r << 6) + c) << 3));
                ra[j5][0] = s4[0];
                ra[j5][1] = s4[1];
            }
        }
    }
    #pragma unroll
    for (int j5 = 0; j5 < 5; ++j5) {
        const int j = j5 * 256 + tid;
        if (j < 1152) {
            const int lrow = j >> 6, c = j & 63;
            bf16x8 v;
            v[0] = f2bf(ra[j5][0].x); v[1] = f2bf(ra[j5][0].y);
            v[2] = f2bf(ra[j5][0].z); v[3] = f2bf(ra[j5][0].w);
            v[4] = f2bf(ra[j5][1].x); v[5] = f2bf(ra[j5][1].y);
            v[6] = f2bf(ra[j5][1].z); v[7] = f2bf(ra[j5][1].w);
            *(bf16x8*)&xbf[lrow][c + 1][0] = v;
        }
    }
    __syncthreads();

    f32x4 ssum = {0.f, 0.f, 0.f, 0.f};  // per-lane relu'd conv sums
    f32x4 acc2 = {0.f, 0.f, 0.f, 0.f};  // per-lane raw x sums (cols<8)

    #pragma unroll 1
    for (int s = 0; s < 4; ++s) {
        // issue loads for strip s+1: image rows 16s+17 .. 16s+32 (async)
        if (s < 3) {
            const int rbase = 16 * s + 17;
            #pragma unroll
            for (int j5 = 0; j5 < 4; ++j5) {
                const int j = j5 * 256 + tid;
                const int lrow = j >> 6, c = j & 63;
                const int r = rbase + lrow;
                ra[j5][0] = z4; ra[j5][1] = z4;
                if (r < 64) {
                    const float4* s4 = (const float4*)(xb + (((r << 6) + c) << 3));
                    ra[j5][0] = s4[0];
                    ra[j5][1] = s4[1];
                }
            }
        }

        // compute strip s: pixels rows 16s..16s+15, read slots (16s..16s+17)%36
        {
            int tb = 16 * s;
            const int sbase = (tb >= NROWS) ? tb - NROWS : tb;   // {0,16,32,12}
            const short* base = &xbf[0][0][0];
            #pragma unroll 2
            for (int rl = 0; rl < 16; ++rl) {
                const int srl = sbase + rl;                       // <= 47
                int t0 = srl + d0; t0 = (t0 >= NROWS) ? t0 - NROWS : t0;
                int t1 = srl + d1; t1 = (t1 >= NROWS) ? t1 - NROWS : t1;
                int t2 = srl + 2;  t2 = (t2 >= NROWS) ? t2 - NROWS : t2;
                const bf16x8 a0 = *(const bf16x8*)(base + t0 * ROWSZ + c0);
                const bf16x8 a1 = *(const bf16x8*)(base + t1 * ROWSZ + c1);
                bf16x8 a2 = {0,0,0,0,0,0,0,0};
                if (g == 0)                                        // only k=64..71 rows matter
                    a2 = *(const bf16x8*)(base + t2 * ROWSZ + c2);
                f32x4 d = {0.f, 0.f, 0.f, 0.f};
                d = __builtin_amdgcn_mfma_f32_16x16x32_bf16(a0, bf0, d, 0, 0, 0);
                d = __builtin_amdgcn_mfma_f32_16x16x32_bf16(a1, bf1, d, 0, 0, 0);
                d = __builtin_amdgcn_mfma_f32_16x16x32_bf16(a2, bf2, d, 0, 0, 0);
                acc2 = __builtin_amdgcn_mfma_f32_16x16x32_bf16(a1, bid, acc2, 0, 0, 0);
                ssum[0] += fmaxf(d[0], 0.f);
                ssum[1] += fmaxf(d[1], 0.f);
                ssum[2] += fmaxf(d[2], 0.f);
                ssum[3] += fmaxf(d[3], 0.f);
            }
        }

        // write staged rows into slots (16s+18 .. 16s+33)%36 — provably
        // disjoint from strip-s read slots, so no barrier needed before.
        if (s < 3) {
            int wt = 16 * s + 18;
            const int wbase = (wt >= NROWS) ? wt - NROWS : wt;    // {18,34,14}
            #pragma unroll
            for (int j5 = 0; j5 < 4; ++j5) {
                const int j = j5 * 256 + tid;
                const int lrow = j >> 6, c = j & 63;
                int ws = wbase + lrow; ws = (ws >= NROWS) ? ws - NROWS : ws;
                bf16x8 v;
                v[0] = f2bf(ra[j5][0].x); v[1] = f2bf(ra[j5][0].y);
                v[2] = f2bf(ra[j5][0].z); v[3] = f2bf(ra[j5][0].w);
                v[4] = f2bf(ra[j5][1].x); v[5] = f2bf(ra[j5][1].y);
                v[6] = f2bf(ra[j5][1].z); v[7] = f2bf(ra[j5][1].w);
                *(bf16x8*)&xbf[ws][c + 1][0] = v;
            }
            __syncthreads();   // new rows visible before next strip's reads
        }
    }

    // ---- reduce over pixels: sum regs, then across lane groups ----
    float scon = ssum[0] + ssum[1] + ssum[2] + ssum[3];
    float sxs  = acc2[0] + acc2[1] + acc2[2] + acc2[3];
    scon += __shfl_xor(scon, 16);
    scon += __shfl_xor(scon, 32);
    sxs  += __shfl_xor(sxs, 16);
    sxs  += __shfl_xor(sxs, 32);
    if (lane < 16) red[wid][lane]  = scon;
    if (lane < 8)  redx[wid][lane] = sxs;
    __syncthreads();
    if (tid < 16) rsum[tid]  = (red[0][tid] + red[1][tid] + red[2][tid] + red[3][tid]) * (1.f / 4096.f);
    if (tid < 8)  rsumx[tid] = (redx[0][tid] + redx[1][tid] + redx[2][tid] + redx[3][tid]) * (1.f / 4096.f);
    __syncthreads();

    if (tid < 16) {
        float acc = rsum[tid];   // cols 0-7: conv1 branch, 8-15: conv3 branch
        #pragma unroll
        for (int ci = 0; ci < 8; ++ci)
            acc += rsumx[ci] * Wsk[e * 128 + ci * 16 + tid];
        pooledS[tid] = acc;
    }
    __syncthreads();

    const float* wd = Wd + (size_t)e * 16 * MM;
    const float* cm = cmask + e * MM;
    #pragma unroll 1
    for (int m = tid; m < MM; m += 256) {
        float acc = 0.f;
        #pragma unroll
        for (int k = 0; k < 16; ++k) acc += pooledS[k] * wd[k * MM + m];
        out[(size_t)b * MM + m] = acc * cm[m];
    }
}

extern "C" void kernel_launch(void* const* d_in, const int* in_sizes, int n_in,
                              void* d_out, int out_size, void* d_ws, size_t ws_size,
                              hipStream_t stream) {
    const float* x    = (const float*)d_in[0];
    const int*   idx  = (const int*)  d_in[1];
    const float* W1   = (const float*)d_in[2];
    const float* W3   = (const float*)d_in[3];
    const float* Wsk  = (const float*)d_in[4];
    const float* Wd   = (const float*)d_in[5];
    const float* cmsk = (const float*)d_in[6];
    float* out = (float*)d_out;

    conv_moe_mfma<<<2048, 256, 0, stream>>>(x, idx, W1, W3, Wsk, Wd, cmsk, out);
}

// Round 6
// 52.295 us; speedup vs baseline: 1.1007x; 1.1007x over previous
//
#include <hip/hip_runtime.h>
#include <hip/hip_bf16.h>

#define MM 512
#define ROWSZ (66 * 8)    // shorts per LDS row (66 cols x 8 ch)

typedef short bf16x8 __attribute__((ext_vector_type(8)));
typedef float f32x4  __attribute__((ext_vector_type(4)));

static __device__ inline short f2bf(float f) {
    __hip_bfloat16 h = __float2bfloat16(f);
    return *reinterpret_cast<short*>(&h);
}

// One block per output row b in [0,2048): e = b>>9, sample = idx[b].
// GEMM per 16-pixel tile: D[16px,16co] = A[16,96] @ B[96,16]
//   B cols 0-7  = W1 (center tap, k=32..39) ; B cols 8-15 = W3 (taps 0..8)
// sx (skip channel sums) via identity-B MFMA on the center-tap A frag.
// pooled = mean relu + (mean x)@Wskip ; out = (pooled@Wd)*mask
//
// Strip buffer: L = 0..17 holds image rows 16s-1 .. 16s+16 (linear, so all
// compute-loop ds_reads keep compile-time immediate offsets — the R5 lesson).
// Each image row is fetched from HBM exactly ONCE: per strip only the 16 new
// rows are fetched; the 2 overlap rows are carried L16,L17 -> L0,L1 via a
// register copy (2 wave ds_reads at end of compute, rewritten after barrier).
// T14 async staging: next strip's global loads issued before compute.
__global__ __launch_bounds__(256, 4)
void conv_moe_mfma(const float* __restrict__ x,
                   const int*   __restrict__ idx,
                   const float* __restrict__ W1,
                   const float* __restrict__ W3,
                   const float* __restrict__ Wsk,
                   const float* __restrict__ Wd,
                   const float* __restrict__ cmask,
                   float*       __restrict__ out)
{
    __shared__ short xbf[18][66][8];   // 19 KB, col halo at 0 and 65
    __shared__ float red[4][16];
    __shared__ float redx[4][8];
    __shared__ float rsum[16];
    __shared__ float rsumx[8];
    __shared__ float pooledS[16];

    const int b    = blockIdx.x;
    const int e    = b >> 9;
    const int tid  = threadIdx.x;
    const int lane = tid & 63;
    const int wid  = tid >> 6;
    const int g    = lane >> 4;   // lane group 0..3
    const int p    = lane & 15;   // A: pixel row; B/D: cout column
    const int CB   = wid << 4;    // this wave's 16-col tile base

    const int samp = idx[b];
    const float* xb = x + (size_t)samp * 32768;

    // ---- B fragments (constant per block) ----
    const float* w3 = W3 + e * 576;  // [tap][cin][cout] (tap=kh*3+kw)
    const float* w1 = W1 + e * 64;   // [cin][cout]
    bf16x8 bf0, bf1, bf2, bid;
    #pragma unroll
    for (int j = 0; j < 8; ++j) {
        float v0 = 0.f, v1 = 0.f, v2 = 0.f, vi = 0.f;
        if (p >= 8) {                       // conv3 couts
            v0 = w3[g * 64 + j * 8 + (p - 8)];             // taps 0..3
            v1 = w3[(4 + g) * 64 + j * 8 + (p - 8)];       // taps 4..7
            if (g == 0) v2 = w3[8 * 64 + j * 8 + (p - 8)]; // tap 8
        } else {                            // conv1 couts (center tap = k 32..39)
            if (g == 0) { v1 = w1[j * 8 + p]; vi = (j == p) ? 1.f : 0.f; }
        }
        bf0[j] = f2bf(v0); bf1[j] = f2bf(v1); bf2[j] = f2bf(v2); bid[j] = f2bf(vi);
    }

    // ---- per-lane A read offsets (in shorts), compile-time row strides ----
    int off0, off1, off2;
    { const int t = g;     const int dr = t / 3, dc = t % 3; off0 = (dr * 66 + CB + p + dc) * 8; }
    { const int t = 4 + g; const int dr = t / 3, dc = t % 3; off1 = (dr * 66 + CB + p + dc) * 8; }
    {                      const int dr = 2,     dc = 2;     off2 = (dr * 66 + CB + p + dc) * 8; }

    // ---- zero column halos once (cols 0 and 65 stay zero forever) ----
    if (tid < 36) {
        const int rr = tid >> 1, side = tid & 1;
        bf16x8 zv = {0,0,0,0,0,0,0,0};
        *(bf16x8*)&xbf[rr][side ? 65 : 0][0] = zv;
    }

    const float4 z4 = make_float4(0.f, 0.f, 0.f, 0.f);
    float4 ra[5][2];

    // ---- initial stage: image rows -1..16 -> L0..L17 (1152 px) ----
    #pragma unroll
    for (int j5 = 0; j5 < 5; ++j5) {
        const int j = j5 * 256 + tid;
        ra[j5][0] = z4; ra[j5][1] = z4;
        if (j < 1152) {
            const int lrow = j >> 6, c = j & 63;
            const int r = lrow - 1;
            if (r >= 0) {
                const float4* s4 = (const float4*)(xb + (((r << 6) + c) << 3));
                ra[j5][0] = s4[0];
                ra[j5][1] = s4[1];
            }
        }
    }
    #pragma unroll
    for (int j5 = 0; j5 < 5; ++j5) {
        const int j = j5 * 256 + tid;
        if (j < 1152) {
            const int lrow = j >> 6, c = j & 63;
            bf16x8 v;
            v[0] = f2bf(ra[j5][0].x); v[1] = f2bf(ra[j5][0].y);
            v[2] = f2bf(ra[j5][0].z); v[3] = f2bf(ra[j5][0].w);
            v[4] = f2bf(ra[j5][1].x); v[5] = f2bf(ra[j5][1].y);
            v[6] = f2bf(ra[j5][1].z); v[7] = f2bf(ra[j5][1].w);
            *(bf16x8*)&xbf[lrow][c + 1][0] = v;
        }
    }
    __syncthreads();

    f32x4 ssum = {0.f, 0.f, 0.f, 0.f};  // per-lane relu'd conv sums
    f32x4 acc2 = {0.f, 0.f, 0.f, 0.f};  // per-lane raw x sums (cols<8)

    #pragma unroll 1
    for (int s = 0; s < 4; ++s) {
        // async: issue global loads for strip s+1's 16 NEW rows
        // (image rows 16(s+1)+1 .. 16(s+1)+16 -> L2..L17)
        if (s < 3) {
            const int rbase = 16 * (s + 1) + 1;
            #pragma unroll
            for (int j5 = 0; j5 < 4; ++j5) {
                const int j = j5 * 256 + tid;
                const int lrow = j >> 6, c = j & 63;
                const int r = rbase + lrow;
                ra[j5][0] = z4; ra[j5][1] = z4;
                if (r < 64) {
                    const float4* s4 = (const float4*)(xb + (((r << 6) + c) << 3));
                    ra[j5][0] = s4[0];
                    ra[j5][1] = s4[1];
                }
            }
        }

        // compute strip s (identical to R4: immediate-offset ds_reads)
        {
            const short* base = &xbf[0][0][0];
            #pragma unroll 2
            for (int rl = 0; rl < 16; ++rl) {
                const short* rbase2 = base + rl * ROWSZ;
                const bf16x8 a0 = *(const bf16x8*)(rbase2 + off0);
                const bf16x8 a1 = *(const bf16x8*)(rbase2 + off1);
                const bf16x8 a2 = *(const bf16x8*)(rbase2 + off2);
                f32x4 d = {0.f, 0.f, 0.f, 0.f};
                d = __builtin_amdgcn_mfma_f32_16x16x32_bf16(a0, bf0, d, 0, 0, 0);
                d = __builtin_amdgcn_mfma_f32_16x16x32_bf16(a1, bf1, d, 0, 0, 0);
                d = __builtin_amdgcn_mfma_f32_16x16x32_bf16(a2, bf2, d, 0, 0, 0);
                acc2 = __builtin_amdgcn_mfma_f32_16x16x32_bf16(a1, bid, acc2, 0, 0, 0);
                ssum[0] += fmaxf(d[0], 0.f);
                ssum[1] += fmaxf(d[1], 0.f);
                ssum[2] += fmaxf(d[2], 0.f);
                ssum[3] += fmaxf(d[3], 0.f);
            }
        }

        // carry the 2 overlap rows (L16,L17 = next strip's L0,L1) in regs
        bf16x8 rcopy;
        if (s < 3 && tid < 128)
            rcopy = *(const bf16x8*)&xbf[16 + (tid >> 6)][(tid & 63) + 1][0];

        __syncthreads();   // all reads of this strip done before overwrite

        if (s < 3) {
            if (tid < 128)
                *(bf16x8*)&xbf[tid >> 6][(tid & 63) + 1][0] = rcopy;
            #pragma unroll
            for (int j5 = 0; j5 < 4; ++j5) {
                const int j = j5 * 256 + tid;
                const int lrow = 2 + (j >> 6), c = j & 63;
                bf16x8 v;
                v[0] = f2bf(ra[j5][0].x); v[1] = f2bf(ra[j5][0].y);
                v[2] = f2bf(ra[j5][0].z); v[3] = f2bf(ra[j5][0].w);
                v[4] = f2bf(ra[j5][1].x); v[5] = f2bf(ra[j5][1].y);
                v[6] = f2bf(ra[j5][1].z); v[7] = f2bf(ra[j5][1].w);
                *(bf16x8*)&xbf[lrow][c + 1][0] = v;
            }
            __syncthreads();   // new strip visible before its reads
        }
    }

    // ---- reduce over pixels: sum regs, then across lane groups ----
    float scon = ssum[0] + ssum[1] + ssum[2] + ssum[3];
    float sxs  = acc2[0] + acc2[1] + acc2[2] + acc2[3];
    scon += __shfl_xor(scon, 16);
    scon += __shfl_xor(scon, 32);
    sxs  += __shfl_xor(sxs, 16);
    sxs  += __shfl_xor(sxs, 32);
    if (lane < 16) red[wid][lane]  = scon;
    if (lane < 8)  redx[wid][lane] = sxs;
    __syncthreads();
    if (tid < 16) rsum[tid]  = (red[0][tid] + red[1][tid] + red[2][tid] + red[3][tid]) * (1.f / 4096.f);
    if (tid < 8)  rsumx[tid] = (redx[0][tid] + redx[1][tid] + redx[2][tid] + redx[3][tid]) * (1.f / 4096.f);
    __syncthreads();

    if (tid < 16) {
        float acc = rsum[tid];   // cols 0-7: conv1 branch, 8-15: conv3 branch
        #pragma unroll
        for (int ci = 0; ci < 8; ++ci)
            acc += rsumx[ci] * Wsk[e * 128 + ci * 16 + tid];
        pooledS[tid] = acc;
    }
    __syncthreads();

    const float* wd = Wd + (size_t)e * 16 * MM;
    const float* cm = cmask + e * MM;
    #pragma unroll 1
    for (int m = tid; m < MM; m += 256) {
        float acc = 0.f;
        #pragma unroll
        for (int k = 0; k < 16; ++k) acc += pooledS[k] * wd[k * MM + m];
        out[(size_t)b * MM + m] = acc * cm[m];
    }
}

extern "C" void kernel_launch(void* const* d_in, const int* in_sizes, int n_in,
                              void* d_out, int out_size, void* d_ws, size_t ws_size,
                              hipStream_t stream) {
    const float* x    = (const float*)d_in[0];
    const int*   idx  = (const int*)  d_in[1];
    const float* W1   = (const float*)d_in[2];
    const float* W3   = (const float*)d_in[3];
    const float* Wsk  = (const float*)d_in[4];
    const float* Wd   = (const float*)d_in[5];
    const float* cmsk = (const float*)d_in[6];
    float* out = (float*)d_out;

    conv_moe_mfma<<<2048, 256, 0, stream>>>(x, idx, W1, W3, Wsk, Wd, cmsk, out);
}